// Round 1
// baseline (1025.278 us; speedup 1.0000x reference)
//
#include <hip/hip_runtime.h>
#include <hip/hip_bf16.h>

typedef unsigned short u16;
typedef unsigned int   u32;

typedef __attribute__((ext_vector_type(8))) __bf16 bf16x8;
typedef __attribute__((ext_vector_type(4))) float  f32x4;

#define NN 4096
#define DD 128
#define EPS 1e-12f

static __device__ __forceinline__ u16 f2bf(float f) {
    union { float f; u32 u; } v; v.f = f;
    u32 r = v.u + 0x7fffu + ((v.u >> 16) & 1u);   // round-to-nearest-even
    return (u16)(r >> 16);
}

// ---------------------------------------------------------------------------
// Edge kernel: one 64-lane wave per edge. val = exp(-||A[c]+case-A[t]||)
// atomicAdd into att[t*N+c] and normsum[t].
// ---------------------------------------------------------------------------
__global__ __launch_bounds__(256) void edge_kernel(
    const int* __restrict__ currents, const int* __restrict__ targets,
    const float* __restrict__ A, const float* __restrict__ cases,
    float* __restrict__ att, float* __restrict__ normsum, int E)
{
    int e = blockIdx.x * 4 + (threadIdx.x >> 6);
    if (e >= E) return;
    int lane = threadIdx.x & 63;
    int c = currents[e];
    int t = targets[e];
    const float2 h2 = *(const float2*)(A + (size_t)c * DD + lane * 2);
    const float2 t2 = *(const float2*)(A + (size_t)t * DD + lane * 2);
    const float2 e2 = *(const float2*)(cases + (size_t)e * DD + lane * 2);
    float d0 = h2.x + e2.x - t2.x;
    float d1 = h2.y + e2.y - t2.y;
    float s = d0 * d0 + d1 * d1;
#pragma unroll
    for (int m = 32; m; m >>= 1) s += __shfl_xor(s, m, 64);
    if (lane == 0) {
        float val = expf(-sqrtf(s));
        atomicAdd(att + (size_t)t * NN + c, val);
        atomicAdd(normsum + t, val);
    }
}

// ---------------------------------------------------------------------------
// rnorm[i] = 1/(normsum[i]+eps)
// ---------------------------------------------------------------------------
__global__ void rnorm_kernel(const float* __restrict__ normsum, float* __restrict__ rnorm)
{
    int i = blockIdx.x * 256 + threadIdx.x;
    rnorm[i] = 1.0f / (normsum[i] + EPS);
}

// ---------------------------------------------------------------------------
// Transpose+convert: in [4096][128] fp32 -> out [128][4096] bf16
// One block per 32 input rows.
// ---------------------------------------------------------------------------
__global__ __launch_bounds__(256) void transpose_to_bf16(
    const float* __restrict__ in, u16* __restrict__ out)
{
    __shared__ __align__(16) u16 lds[128][40];
    const int k0 = blockIdx.x * 32;
    const int t = threadIdx.x;
#pragma unroll
    for (int i = 0; i < 4; ++i) {
        int f  = t + 256 * i;          // float4 index 0..1023 in the 32x128 tile
        int kr = f >> 5;               // 0..31
        int n0 = (f & 31) * 4;         // 0..124
        float4 v = *(const float4*)(in + (size_t)(k0 + kr) * DD + n0);
        lds[n0 + 0][kr] = f2bf(v.x);
        lds[n0 + 1][kr] = f2bf(v.y);
        lds[n0 + 2][kr] = f2bf(v.z);
        lds[n0 + 3][kr] = f2bf(v.w);
    }
    __syncthreads();
    int n = t >> 1, h = t & 1;         // n 0..127, h 0..1 (16 k-elems each)
    uint4 v0 = *(const uint4*)&lds[n][h * 16];
    uint4 v1 = *(const uint4*)&lds[n][h * 16 + 8];
    *(uint4*)(out + (size_t)n * NN + k0 + h * 16)     = v0;
    *(uint4*)(out + (size_t)n * NN + k0 + h * 16 + 8) = v1;
}

// ---------------------------------------------------------------------------
// Skinny GEMM: C[4096][128] = Amat[4096][4096](fp32, converted to bf16 in
// staging) @ B, with B given pre-transposed as BT[128][4096] bf16.
// applyEpi: C = acc * rnorm[row] + resid[row][col]
// BM=16, BN=128 (full), BK=32. 256 blocks, 256 threads (4 waves).
// Wave w covers cols w*32..w*32+31 (2 n-tiles), all 16 rows.
// ---------------------------------------------------------------------------
__global__ __launch_bounds__(256) void gemm_skinny(
    const float* __restrict__ Amat,   // [4096][4096]
    const u16*   __restrict__ BT,     // [128][4096] bf16 bits
    const float* __restrict__ rnorm,  // [4096] or null
    const float* __restrict__ resid,  // [4096][128] or null
    float* __restrict__ C,            // [4096][128]
    int applyEpi)
{
    __shared__ __align__(16) u16 As[16 * 40];   // row m, 32 k, stride 40
    __shared__ __align__(16) u16 Bs[128 * 40];  // row n, 32 k, stride 40

    const int m0   = blockIdx.x * 16;
    const int t    = threadIdx.x;
    const int wave = t >> 6;
    const int lane = t & 63;
    const int quad = lane >> 4;
    const int l16  = lane & 15;
    const int nw   = wave * 32;

    f32x4 acc0 = {0.f, 0.f, 0.f, 0.f};
    f32x4 acc1 = {0.f, 0.f, 0.f, 0.f};

    for (int k0 = 0; k0 < NN; k0 += 32) {
        // stage A tile: 16 rows x 32 floats = 128 float4 loads, fp32->bf16
        if (t < 128) {
            int r = t >> 3, q = t & 7;
            float4 v = *(const float4*)(Amat + (size_t)(m0 + r) * NN + k0 + q * 4);
            ushort4 u;
            u.x = f2bf(v.x); u.y = f2bf(v.y); u.z = f2bf(v.z); u.w = f2bf(v.w);
            *(ushort4*)&As[r * 40 + q * 4] = u;
        }
        // stage B tile: 128 rows x 32 bf16 = 512 16B chunks
#pragma unroll
        for (int i = 0; i < 2; ++i) {
            int idx = t + 256 * i;
            int n = idx >> 2, q = idx & 3;
            uint4 v = *(const uint4*)(BT + (size_t)n * NN + k0 + q * 8);
            *(uint4*)&Bs[n * 40 + q * 8] = v;
        }
        __syncthreads();

        bf16x8 a  = *(const bf16x8*)&As[l16 * 40 + quad * 8];
        bf16x8 b0 = *(const bf16x8*)&Bs[(nw + l16) * 40 + quad * 8];
        bf16x8 b1 = *(const bf16x8*)&Bs[(nw + 16 + l16) * 40 + quad * 8];
        acc0 = __builtin_amdgcn_mfma_f32_16x16x32_bf16(a, b0, acc0, 0, 0, 0);
        acc1 = __builtin_amdgcn_mfma_f32_16x16x32_bf16(a, b1, acc1, 0, 0, 0);
        __syncthreads();
    }

    // epilogue: D layout col=lane&15, row=quad*4+reg
#pragma unroll
    for (int r = 0; r < 4; ++r) {
        int rr = m0 + quad * 4 + r;
        int c0 = nw + l16;
        int c1 = nw + 16 + l16;
        float v0 = acc0[r], v1 = acc1[r];
        if (applyEpi) {
            float sc = rnorm[rr];
            v0 = v0 * sc + resid[(size_t)rr * DD + c0];
            v1 = v1 * sc + resid[(size_t)rr * DD + c1];
        }
        C[(size_t)rr * DD + c0] = v0;
        C[(size_t)rr * DD + c1] = v1;
    }
}

// ---------------------------------------------------------------------------
extern "C" void kernel_launch(void* const* d_in, const int* in_sizes, int n_in,
                              void* d_out, int out_size, void* d_ws, size_t ws_size,
                              hipStream_t stream)
{
    const int*   currents = (const int*)d_in[0];
    const int*   targets  = (const int*)d_in[1];
    const float* acts     = (const float*)d_in[2];   // [4096][128]
    const float* cases    = (const float*)d_in[3];   // [E][128]
    const float* W        = (const float*)d_in[4];   // [4096][4096]
    float*       out      = (float*)d_out;           // [4096][128]
    const int E = in_sizes[0];

    // workspace layout
    char* ws = (char*)d_ws;
    float* att     = (float*)ws;                                   // 64 MB
    float* feat    = (float*)(ws + (size_t)NN * NN * 4);           // 2 MB
    u16*   BT1     = (u16*)((char*)feat + (size_t)NN * DD * 4);    // 1 MB
    u16*   BT2     = (u16*)((char*)BT1 + (size_t)DD * NN * 2);     // 1 MB
    float* normsum = (float*)((char*)BT2 + (size_t)DD * NN * 2);   // 16 KB
    float* rnorm   = normsum + NN;                                 // 16 KB

    hipMemsetAsync(att, 0, (size_t)NN * NN * 4, stream);
    hipMemsetAsync(normsum, 0, (size_t)NN * 4, stream);

    // BT1 = bf16(acts^T) — independent of edge pass
    transpose_to_bf16<<<128, 256, 0, stream>>>(acts, BT1);

    // edge scatter (+ per-target norm accumulation)
    edge_kernel<<<(E + 3) / 4, 256, 0, stream>>>(currents, targets, acts, cases,
                                                 att, normsum, E);
    rnorm_kernel<<<NN / 256, 256, 0, stream>>>(normsum, rnorm);

    // feat = W @ acts
    gemm_skinny<<<NN / 16, 256, 0, stream>>>(W, BT1, nullptr, nullptr, feat, 0);

    // BT2 = bf16(feat^T)
    transpose_to_bf16<<<128, 256, 0, stream>>>(feat, BT2);

    // out = rnorm ⊙ (att @ feat) + feat
    gemm_skinny<<<NN / 16, 256, 0, stream>>>(att, BT2, rnorm, feat, out, 1);
}

// Round 2
// 787.308 us; speedup vs baseline: 1.3023x; 1.3023x over previous
//
#include <hip/hip_runtime.h>
#include <hip/hip_bf16.h>

typedef unsigned short u16;
typedef unsigned int   u32;

typedef __attribute__((ext_vector_type(8))) __bf16 bf16x8;
typedef __attribute__((ext_vector_type(4))) float  f32x4;

#define NN 4096
#define DD 128
#define EPS 1e-12f

#define KS 4            // split-K factor
#define BM 32           // rows per block
#define BK 64           // k per stage
#define KPER (NN / KS)  // 1024
#define LDK 72          // padded LDS row stride (u16), 144 B (16B-aligned)

static __device__ __forceinline__ u16 f2bf(float f) {
    union { float f; u32 u; } v; v.f = f;
    u32 r = v.u + 0x7fffu + ((v.u >> 16) & 1u);   // round-to-nearest-even
    return (u16)(r >> 16);
}

// ---------------------------------------------------------------------------
// Edge kernel: 32 lanes per edge (2 edges per wave).
// val = exp(-||A[c]+case-A[t]||); atomicAdd att[t*N+c], normsum[t].
// ---------------------------------------------------------------------------
__global__ __launch_bounds__(256) void edge_kernel(
    const int* __restrict__ currents, const int* __restrict__ targets,
    const float* __restrict__ A, const float* __restrict__ cases,
    float* __restrict__ att, float* __restrict__ normsum, int E)
{
    int e = blockIdx.x * 8 + (threadIdx.x >> 5);
    if (e >= E) return;
    int l = threadIdx.x & 31;
    int c = currents[e];
    int t = targets[e];
    float4 h = *(const float4*)(A + (size_t)c * DD + l * 4);
    float4 g = *(const float4*)(A + (size_t)t * DD + l * 4);
    float4 q = *(const float4*)(cases + (size_t)e * DD + l * 4);
    float d0 = h.x + q.x - g.x;
    float d1 = h.y + q.y - g.y;
    float d2 = h.z + q.z - g.z;
    float d3 = h.w + q.w - g.w;
    float s = d0 * d0 + d1 * d1 + d2 * d2 + d3 * d3;
#pragma unroll
    for (int m = 16; m; m >>= 1) s += __shfl_xor(s, m, 64);
    if (l == 0) {
        float val = __expf(-__fsqrt_rn(s));
        atomicAdd(att + (size_t)t * NN + c, val);
        atomicAdd(normsum + t, val);
    }
}

// ---------------------------------------------------------------------------
__global__ void rnorm_kernel(const float* __restrict__ normsum, float* __restrict__ rnorm)
{
    int i = blockIdx.x * 256 + threadIdx.x;
    rnorm[i] = 1.0f / (normsum[i] + EPS);
}

// ---------------------------------------------------------------------------
// Transpose+convert: in [4096][128] fp32 -> out [128][4096] bf16
// ---------------------------------------------------------------------------
__global__ __launch_bounds__(256) void transpose_to_bf16(
    const float* __restrict__ in, u16* __restrict__ out)
{
    __shared__ __align__(16) u16 lds[128][40];
    const int k0 = blockIdx.x * 32;
    const int t = threadIdx.x;
#pragma unroll
    for (int i = 0; i < 4; ++i) {
        int f  = t + 256 * i;
        int kr = f >> 5;
        int n0 = (f & 31) * 4;
        float4 v = *(const float4*)(in + (size_t)(k0 + kr) * DD + n0);
        lds[n0 + 0][kr] = f2bf(v.x);
        lds[n0 + 1][kr] = f2bf(v.y);
        lds[n0 + 2][kr] = f2bf(v.z);
        lds[n0 + 3][kr] = f2bf(v.w);
    }
    __syncthreads();
    int n = t >> 1, h = t & 1;
    uint4 v0 = *(const uint4*)&lds[n][h * 16];
    uint4 v1 = *(const uint4*)&lds[n][h * 16 + 8];
    *(uint4*)(out + (size_t)n * NN + k0 + h * 16)     = v0;
    *(uint4*)(out + (size_t)n * NN + k0 + h * 16 + 8) = v1;
}

// ---------------------------------------------------------------------------
// Split-K skinny GEMM: part[ks] = Amat[m0:m0+32, ks*1024:(ks+1)*1024] @ B
// Amat fp32 (converted to bf16 in staging), BT bf16 [128][4096] (B^T).
// 512 threads = 8 waves; wave w covers n-cols w*16..w*16+15, both 16-row
// m-tiles. Grid (128, KS) -> 512 blocks = 2 blocks/CU, 16 waves/CU.
// ---------------------------------------------------------------------------
__global__ __launch_bounds__(512) void gemm_splitk(
    const float* __restrict__ Amat,   // [4096][4096]
    const u16*   __restrict__ BT,     // [128][4096]
    float* __restrict__ part)         // [KS][4096][128]
{
    __shared__ __align__(16) u16 As[BM * LDK];
    __shared__ __align__(16) u16 Bs[DD * LDK];

    const int m0   = blockIdx.x * BM;
    const int ks   = blockIdx.y;
    const int kbeg = ks * KPER;
    const int t    = threadIdx.x;
    const int wave = t >> 6;
    const int lane = t & 63;
    const int quad = lane >> 4;
    const int l16  = lane & 15;

    // staging indices
    const int ar = t >> 4;   // 0..31 (A row)
    const int aq = t & 15;   // float4 within row (16*4 = 64 floats)
    const int bn = t >> 3;   // 0..63 (B row, +64 for second)
    const int bq = t & 7;    // uint4 chunk (8*8 = 64 elems)

    f32x4 acc0 = {0.f, 0.f, 0.f, 0.f};
    f32x4 acc1 = {0.f, 0.f, 0.f, 0.f};

    for (int kk = 0; kk < KPER; kk += BK) {
        const int k0 = kbeg + kk;
        float4 v = *(const float4*)(Amat + (size_t)(m0 + ar) * NN + k0 + aq * 4);
        ushort4 u;
        u.x = f2bf(v.x); u.y = f2bf(v.y); u.z = f2bf(v.z); u.w = f2bf(v.w);
        *(ushort4*)&As[ar * LDK + aq * 4] = u;
        uint4 b0 = *(const uint4*)(BT + (size_t)bn * NN + k0 + bq * 8);
        uint4 b1 = *(const uint4*)(BT + (size_t)(bn + 64) * NN + k0 + bq * 8);
        *(uint4*)&Bs[bn * LDK + bq * 8] = b0;
        *(uint4*)&Bs[(bn + 64) * LDK + bq * 8] = b1;
        __syncthreads();
#pragma unroll
        for (int k2 = 0; k2 < 2; ++k2) {
            bf16x8 a0 = *(const bf16x8*)&As[l16 * LDK + k2 * 32 + quad * 8];
            bf16x8 a1 = *(const bf16x8*)&As[(16 + l16) * LDK + k2 * 32 + quad * 8];
            bf16x8 b  = *(const bf16x8*)&Bs[(wave * 16 + l16) * LDK + k2 * 32 + quad * 8];
            acc0 = __builtin_amdgcn_mfma_f32_16x16x32_bf16(a0, b, acc0, 0, 0, 0);
            acc1 = __builtin_amdgcn_mfma_f32_16x16x32_bf16(a1, b, acc1, 0, 0, 0);
        }
        __syncthreads();
    }

    // D layout: col = lane&15 (within wave's 16-col tile), row = quad*4+reg
    float* P = part + (size_t)ks * NN * DD;
#pragma unroll
    for (int r = 0; r < 4; ++r) {
        int row0 = m0 + quad * 4 + r;
        int col  = wave * 16 + l16;
        P[(size_t)row0 * DD + col]        = acc0[r];
        P[(size_t)(row0 + 16) * DD + col] = acc1[r];
    }
}

// ---------------------------------------------------------------------------
// feat = sum of KS partials
// ---------------------------------------------------------------------------
__global__ __launch_bounds__(256) void combine_feat(
    const float* __restrict__ part, float* __restrict__ feat)
{
    int i = blockIdx.x * 256 + threadIdx.x;   // float4 index, NN*DD/4 total
    const float4* p = (const float4*)part;
    const int S = NN * DD / 4;
    float4 a = p[i], b = p[i + S], c = p[i + 2 * S], d = p[i + 3 * S];
    float4 s;
    s.x = (a.x + b.x) + (c.x + d.x);
    s.y = (a.y + b.y) + (c.y + d.y);
    s.z = (a.z + b.z) + (c.z + d.z);
    s.w = (a.w + b.w) + (c.w + d.w);
    ((float4*)feat)[i] = s;
}

// ---------------------------------------------------------------------------
// out = (sum of KS partials) * rnorm[row] + feat
// ---------------------------------------------------------------------------
__global__ __launch_bounds__(256) void combine_out(
    const float* __restrict__ part, const float* __restrict__ rnorm,
    const float* __restrict__ feat, float* __restrict__ out)
{
    int i = blockIdx.x * 256 + threadIdx.x;   // float4 index
    int row = i >> 5;                          // 32 float4 per 128-col row
    const float4* p = (const float4*)part;
    const int S = NN * DD / 4;
    float4 a = p[i], b = p[i + S], c = p[i + 2 * S], d = p[i + 3 * S];
    float sc = rnorm[row];
    float4 f = ((const float4*)feat)[i];
    float4 s;
    s.x = ((a.x + b.x) + (c.x + d.x)) * sc + f.x;
    s.y = ((a.y + b.y) + (c.y + d.y)) * sc + f.y;
    s.z = ((a.z + b.z) + (c.z + d.z)) * sc + f.z;
    s.w = ((a.w + b.w) + (c.w + d.w)) * sc + f.w;
    ((float4*)out)[i] = s;
}

// ---------------------------------------------------------------------------
extern "C" void kernel_launch(void* const* d_in, const int* in_sizes, int n_in,
                              void* d_out, int out_size, void* d_ws, size_t ws_size,
                              hipStream_t stream)
{
    const int*   currents = (const int*)d_in[0];
    const int*   targets  = (const int*)d_in[1];
    const float* acts     = (const float*)d_in[2];   // [4096][128]
    const float* cases    = (const float*)d_in[3];   // [E][128]
    const float* W        = (const float*)d_in[4];   // [4096][4096]
    float*       out      = (float*)d_out;           // [4096][128]
    const int E = in_sizes[0];

    // workspace layout
    char* ws = (char*)d_ws;
    float* att     = (float*)ws;                                     // 64 MB
    float* part    = (float*)(ws + (size_t)NN * NN * 4);             // KS*2 MB
    float* feat    = part + (size_t)KS * NN * DD;                    // 2 MB
    u16*   BT1     = (u16*)(feat + (size_t)NN * DD);                 // 1 MB
    u16*   BT2     = BT1 + (size_t)DD * NN;                          // 1 MB
    float* normsum = (float*)(BT2 + (size_t)DD * NN);                // 16 KB
    float* rnorm   = normsum + NN;                                   // 16 KB

    hipMemsetAsync(att, 0, (size_t)NN * NN * 4, stream);
    hipMemsetAsync(normsum, 0, (size_t)NN * 4, stream);

    // BT1 = bf16(acts^T)
    transpose_to_bf16<<<128, 256, 0, stream>>>(acts, BT1);

    // edge scatter (+ per-target norm accumulation)
    edge_kernel<<<(E + 7) / 8, 256, 0, stream>>>(currents, targets, acts, cases,
                                                 att, normsum, E);
    rnorm_kernel<<<NN / 256, 256, 0, stream>>>(normsum, rnorm);

    // feat = W @ acts  (split-K partials, then combine)
    gemm_splitk<<<dim3(NN / BM, KS), 512, 0, stream>>>(W, BT1, part);
    combine_feat<<<NN * DD / 4 / 256, 256, 0, stream>>>(part, feat);

    // BT2 = bf16(feat^T)
    transpose_to_bf16<<<128, 256, 0, stream>>>(feat, BT2);

    // out = rnorm ⊙ (att @ feat) + feat
    gemm_splitk<<<dim3(NN / BM, KS), 512, 0, stream>>>(att, BT2, part);
    combine_out<<<NN * DD / 4 / 256, 256, 0, stream>>>(part, rnorm, feat, out);
}